// Round 4
// baseline (788.844 us; speedup 1.0000x reference)
//
#include <hip/hip_runtime.h>

// ---------------------------------------------------------------------------
// BlockGNN on MI355X, round 4: XCD-sharded bf16 gather (R3 + compile fix:
// nontemporal store via ext_vector_type instead of HIP uint4 class).
//   - u_j = s_j * (h_j + res_j) stored bf16 -> aggregation is pure gather-sum
//   - aggregation split into 8 channel groups pinned to XCDs (blockIdx.x % 8)
//     so each XCD's gather working set (3.2 MB) fits its 4 MiB L2
//   - col loads + out stores nontemporal to avoid polluting the hot u slice
//   - MFMA bf16 GEMM with fused bias/relu/residual/scale epilogue
// ---------------------------------------------------------------------------

typedef __bf16 bf16x8 __attribute__((ext_vector_type(8)));
typedef float f32x4 __attribute__((ext_vector_type(4)));
typedef unsigned int u32x4 __attribute__((ext_vector_type(4)));

__device__ inline float bf2f(unsigned short u) {
  union { unsigned int i; float f; } v;
  v.i = (unsigned int)u << 16;
  return v.f;
}
__device__ inline unsigned short f2bf(float f) {
  union { unsigned int i; float f; } v;
  v.f = f;
  unsigned int i = v.i;
  return (unsigned short)((i + 0x7fffu + ((i >> 16) & 1u)) >> 16);  // RNE
}
__device__ inline unsigned int pack2(float a, float b) {
  return (unsigned int)f2bf(a) | ((unsigned int)f2bf(b) << 16);
}
__device__ inline void acc8(float* acc, u32x4 r) {
#pragma unroll
  for (int q = 0; q < 4; ++q) {
    acc[2 * q] += bf2f((unsigned short)(r[q] & 0xffffu));
    acc[2 * q + 1] += bf2f((unsigned short)(r[q] >> 16));
  }
}

// ----------------------------- CSR build -----------------------------------

__global__ void count_deg_kernel(const int* __restrict__ dst, int* __restrict__ deg, int E) {
  int e = blockIdx.x * blockDim.x + threadIdx.x;
  if (e < E) atomicAdd(&deg[dst[e]], 1);
}

__global__ void scan_partial_kernel(const int* __restrict__ deg, int* __restrict__ bsum, int N) {
  __shared__ int s[256];
  int i = blockIdx.x * 256 + threadIdx.x;
  s[threadIdx.x] = (i < N) ? deg[i] : 0;
  __syncthreads();
  for (int off = 128; off > 0; off >>= 1) {
    if (threadIdx.x < off) s[threadIdx.x] += s[threadIdx.x + off];
    __syncthreads();
  }
  if (threadIdx.x == 0) bsum[blockIdx.x] = s[0];
}

__global__ void scan_block_kernel(const int* __restrict__ bsum, int* __restrict__ boff,
                                  int* __restrict__ row_off, int NB, int N) {
  __shared__ int s[256];
  int v = (threadIdx.x < NB) ? bsum[threadIdx.x] : 0;
  s[threadIdx.x] = v;
  __syncthreads();
  for (int off = 1; off < 256; off <<= 1) {
    int t = (threadIdx.x >= off) ? s[threadIdx.x - off] : 0;
    __syncthreads();
    s[threadIdx.x] += t;
    __syncthreads();
  }
  boff[threadIdx.x] = s[threadIdx.x] - v;
  if (threadIdx.x == 255) row_off[N] = s[255];
}

// also computes inv_s and initializes cursor = row_off (saves 2 dispatches)
__global__ void scan_final_kernel(const int* __restrict__ deg, const int* __restrict__ boff,
                                  int* __restrict__ row_off, int* __restrict__ cursor,
                                  float* __restrict__ inv_s, int N) {
  __shared__ int s[256];
  int i = blockIdx.x * 256 + threadIdx.x;
  int v = (i < N) ? deg[i] : 0;
  s[threadIdx.x] = v;
  __syncthreads();
  for (int off = 1; off < 256; off <<= 1) {
    int t = (threadIdx.x >= off) ? s[threadIdx.x - off] : 0;
    __syncthreads();
    s[threadIdx.x] += t;
    __syncthreads();
  }
  if (i < N) {
    int ro = boff[blockIdx.x] + s[threadIdx.x] - v;
    row_off[i] = ro;
    cursor[i] = ro;
    inv_s[i] = rsqrtf((float)(v + 1));  // +1 self loop
  }
}

__global__ void fill_csr_kernel(const int* __restrict__ src, const int* __restrict__ dst,
                                int* __restrict__ cursor, int* __restrict__ col, int E) {
  int e = blockIdx.x * blockDim.x + threadIdx.x;
  if (e < E) {
    int pos = atomicAdd(&cursor[dst[e]], 1);
    col[pos] = src[e];
  }
}

// ----------------------------- prep ----------------------------------------

__global__ void prep_ux_kernel(const float* __restrict__ x, const float* __restrict__ inv_s,
                               unsigned short* __restrict__ u, int total) {
  int idx = blockIdx.x * 256 + threadIdx.x;
  if (idx < total) {
    int i = idx >> 7;
    u[idx] = f2bf(inv_s[i] * x[idx]);
  }
}

// Wt[n][k] = bf16( W[k][n] );  W is [K][Ncol] row-major
__global__ void transpose_w_kernel(const float* __restrict__ W, unsigned short* __restrict__ Wt,
                                   int K, int Ncol) {
  int idx = blockIdx.x * 256 + threadIdx.x;
  if (idx < K * Ncol) {
    int k = idx / Ncol, n = idx - k * Ncol;
    Wt[n * K + k] = f2bf(W[idx]);
  }
}

// all L layers of Ws at once: W [L][K][Ncol] -> Wt [L][Ncol][K]
__global__ void transpose_ws_kernel(const float* __restrict__ W, unsigned short* __restrict__ Wt,
                                    int K, int Ncol, int total) {
  int idx = blockIdx.x * 256 + threadIdx.x;
  if (idx < total) {
    int l = idx / (K * Ncol);
    int rem = idx - l * K * Ncol;
    int k = rem / Ncol, n = rem - k * Ncol;
    Wt[l * K * Ncol + n * K + k] = f2bf(W[idx]);
  }
}

// ----------------------------- aggregate ------------------------------------
// out_i[g-slice] = bf16( s_i * ( u_i + sum_{j in in(i)} u_j ) )  for channel
// group g = blockIdx.x (8 groups -> round-robin XCD pinning).
// Wave handles 4 nodes (16 lanes each); within a node: SLOTS edge slots x LPR
// 16B-lanes; cross-slot reduction = shfl_down within the 16-lane row (DPP).
template <int CH, int CHG>
__global__ __launch_bounds__(256) void aggregate_kernel(
    const unsigned short* __restrict__ u, const int* __restrict__ row_off,
    const int* __restrict__ col, const float* __restrict__ inv_s,
    unsigned short* __restrict__ out, int N) {
  constexpr int LPR = CHG / 8;     // lanes per row-slice (16B each): 4 or 2
  constexpr int SLOTS = 16 / LPR;  // edge slots per node: 4 or 8
  int g = blockIdx.x;
  int lane = threadIdx.x & 63;
  int wave = threadIdx.x >> 6;
  int i = blockIdx.y * 16 + wave * 4 + (lane >> 4);
  if (i >= N) return;
  int l16 = lane & 15;
  int sub = l16 / LPR;
  int c = l16 % LPR;
  const unsigned short* ug = u + g * CHG + c * 8;
  int e0 = row_off[i], e1 = row_off[i + 1];
  float acc[8] = {};
  for (int e = e0 + sub; e < e1; e += SLOTS) {
    int j = __builtin_nontemporal_load(&col[e]);
    u32x4 r = *(const u32x4*)&ug[(size_t)j * CH];
    acc8(acc, r);
  }
#pragma unroll
  for (int k = 0; k < 8; ++k) {
#pragma unroll
    for (int off = 8; off >= LPR; off >>= 1) acc[k] += __shfl_down(acc[k], off);
  }
  if (l16 < LPR) {
    u32x4 self = *(const u32x4*)&ug[(size_t)i * CH];
    acc8(acc, self);
    float s = inv_s[i];
    u32x4 o;
    o[0] = pack2(s * acc[0], s * acc[1]);
    o[1] = pack2(s * acc[2], s * acc[3]);
    o[2] = pack2(s * acc[4], s * acc[5]);
    o[3] = pack2(s * acc[6], s * acc[7]);
    __builtin_nontemporal_store(o, (u32x4*)&out[(size_t)i * CH + g * CHG + c * 8]);
  }
}

// ----------------------------- MFMA GEMM ------------------------------------
// C[M,256] = A[M,K] @ W[K,256] (+bias, opt relu)
// WRITE_U: out = bf16( inv_s[r] * (C + gh[batch[r]]) )   (next layer's u)
// else:    out = bf16( C )                               (final h)
template <int K, bool RELU, bool WRITE_U>
__global__ __launch_bounds__(256) void gemm_kernel(
    const unsigned short* __restrict__ A,   // [M][K] bf16
    const unsigned short* __restrict__ Bt,  // [256][K] bf16 (W transposed)
    const float* __restrict__ bias,         // [256]
    const float* __restrict__ inv_s, const int* __restrict__ batch,
    const float* __restrict__ gh,           // [G][256]
    unsigned short* __restrict__ out,       // [M][256] bf16
    int M) {
  constexpr int BK = 32;
  constexpr int LDT = 40;  // padded stride in ushorts (80B, 16B-aligned)
  __shared__ unsigned short As[64 * LDT];
  __shared__ unsigned short Bs[256 * LDT];
  int tid = threadIdx.x;
  int wave = tid >> 6, lane = tid & 63;
  int quad = lane >> 4, l15 = lane & 15;
  int row0 = blockIdx.x * 64;
  f32x4 acc[4][4];
#pragma unroll
  for (int m = 0; m < 4; ++m)
#pragma unroll
    for (int n = 0; n < 4; ++n) acc[m][n] = (f32x4){0.f, 0.f, 0.f, 0.f};

  for (int k0 = 0; k0 < K; k0 += BK) {
    {  // stage A: 64 rows x 32 k
      int r = tid >> 2, kq = tid & 3;
      int gr = row0 + r;
      u32x4 v = (u32x4){0u, 0u, 0u, 0u};
      if (gr < M) v = *(const u32x4*)&A[(size_t)gr * K + k0 + kq * 8];
      *(u32x4*)&As[r * LDT + kq * 8] = v;
    }
#pragma unroll
    for (int p = 0; p < 4; ++p) {  // stage B: 256 rows x 32 k
      int n = (tid >> 2) + p * 64, kq = tid & 3;
      *(u32x4*)&Bs[n * LDT + kq * 8] = *(const u32x4*)&Bt[(size_t)n * K + k0 + kq * 8];
    }
    __syncthreads();
    bf16x8 af[4], bfr[4];
#pragma unroll
    for (int m = 0; m < 4; ++m)
      af[m] = __builtin_bit_cast(bf16x8, *(const u32x4*)&As[(m * 16 + l15) * LDT + quad * 8]);
#pragma unroll
    for (int n = 0; n < 4; ++n)
      bfr[n] = __builtin_bit_cast(bf16x8,
                                  *(const u32x4*)&Bs[(wave * 64 + n * 16 + l15) * LDT + quad * 8]);
#pragma unroll
    for (int m = 0; m < 4; ++m)
#pragma unroll
      for (int n = 0; n < 4; ++n)
        acc[m][n] = __builtin_amdgcn_mfma_f32_16x16x32_bf16(af[m], bfr[n], acc[m][n], 0, 0, 0);
    __syncthreads();
  }
  // epilogue: C/D map col=lane&15, row=(lane>>4)*4+reg
#pragma unroll
  for (int m = 0; m < 4; ++m) {
#pragma unroll
    for (int r = 0; r < 4; ++r) {
      int gr = row0 + m * 16 + quad * 4 + r;
      if (gr >= M) continue;
      float sv = 1.0f;
      int bofs = 0;
      if (WRITE_U) {
        sv = inv_s[gr];
        bofs = batch[gr] * 256;
      }
#pragma unroll
      for (int n = 0; n < 4; ++n) {
        int cc = wave * 64 + n * 16 + l15;
        float v = acc[m][n][r] + bias[cc];
        if (RELU) v = fmaxf(v, 0.f);
        if (WRITE_U) v = sv * (v + gh[bofs + cc]);
        out[(size_t)gr * 256 + cc] = f2bf(v);
      }
    }
  }
}

// ----------------------------- pool + final ---------------------------------

__global__ void pool_kernel(const unsigned short* __restrict__ h, const int* __restrict__ batch,
                            float* __restrict__ gmsum, float* __restrict__ cnt, int N, int chunk) {
  int start = blockIdx.x * chunk;
  int end = min(start + chunk, N);
  if (start >= end) return;
  int c = threadIdx.x;
  int g = batch[start];
  float acc = 0.0f;
  int run = 0;
  for (int n = start; n < end; ++n) {
    int bg = batch[n];
    if (bg != g) {
      atomicAdd(&gmsum[g * 256 + c], acc);
      if (c == 0) atomicAdd(&cnt[g], (float)run);
      acc = 0.0f;
      run = 0;
      g = bg;
    }
    acc += bf2f(h[(size_t)n * 256 + c]);
    run++;
  }
  atomicAdd(&gmsum[g * 256 + c], acc);
  if (c == 0) atomicAdd(&cnt[g], (float)run);
}

__global__ void final_kernel(const float* __restrict__ gmsum, const float* __restrict__ cnt,
                             const float* __restrict__ gh, const float* __restrict__ Wlin,
                             const float* __restrict__ blin, float* __restrict__ y,
                             float* __restrict__ gm_out, int G) {
  int g = blockIdx.x;
  int c = threadIdx.x;
  __shared__ float row[256];
  float v = gmsum[g * 256 + c] / fmaxf(cnt[g], 1.0f) + gh[g * 256 + c];
  gm_out[g * 256 + c] = v;
  row[c] = v;
  __syncthreads();
  if (c < 10) {
    float acc = blin[c];
    for (int k = 0; k < 256; ++k) acc += row[k] * Wlin[k * 10 + c];
    y[g * 10 + c] = acc;
  }
}

// ----------------------------- launch ----------------------------------------

extern "C" void kernel_launch(void* const* d_in, const int* in_sizes, int n_in,
                              void* d_out, int out_size, void* d_ws, size_t ws_size,
                              hipStream_t stream) {
  const float* x = (const float*)d_in[0];
  const int* ei = (const int*)d_in[1];
  const int* batch = (const int*)d_in[2];
  const float* gh = (const float*)d_in[3];
  const float* W0 = (const float*)d_in[4];
  const float* b0 = (const float*)d_in[5];
  const float* Ws = (const float*)d_in[6];
  const float* bs = (const float*)d_in[7];
  const float* Wlin = (const float*)d_in[8];
  const float* blin = (const float*)d_in[9];
  float* out = (float*)d_out;

  const int N = in_sizes[2];
  const int E = in_sizes[1] / 2;
  const int G = in_sizes[3] / 256;
  const int H = 256, L = 3, C = 10, F = 128;

  char* ws = (char*)d_ws;
  size_t off = 0;
  auto alloc = [&](size_t bytes) {
    void* p = ws + off;
    off += (bytes + 255) & ~(size_t)255;
    return p;
  };
  int* deg = (int*)alloc((size_t)N * 4);
  int* cursor = (int*)alloc((size_t)N * 4);
  int* row_off = (int*)alloc((size_t)(N + 1) * 4);
  int* bsum = (int*)alloc(256 * 4);
  int* boff = (int*)alloc(256 * 4);
  int* col = (int*)alloc((size_t)E * 4);
  float* inv_s = (float*)alloc((size_t)N * 4);
  float* cnt = (float*)alloc((size_t)G * 4);
  float* gmsum = (float*)alloc((size_t)G * H * 4);
  unsigned short* u_x = (unsigned short*)alloc((size_t)N * F * 2);   // s*x
  unsigned short* uA = (unsigned short*)alloc((size_t)N * H * 2);    // s*(h+res)
  unsigned short* aggA = (unsigned short*)alloc((size_t)N * H * 2);  // agg out / GEMM A
  unsigned short* hfin = (unsigned short*)alloc((size_t)N * H * 2);  // final h
  unsigned short* Wt0 = (unsigned short*)alloc((size_t)F * H * 2);   // [256][128]
  unsigned short* WtS = (unsigned short*)alloc((size_t)L * H * H * 2);

  const int* srcv = ei;
  const int* dstv = ei + E;

  (void)hipMemsetAsync(deg, 0, (size_t)N * 4, stream);
  (void)hipMemsetAsync(cnt, 0, (size_t)(((char*)gmsum - (char*)cnt)) + (size_t)G * H * 4, stream);

  int EB = (E + 255) / 256;
  int NB = (N + 255) / 256;
  count_deg_kernel<<<EB, 256, 0, stream>>>(dstv, deg, E);
  scan_partial_kernel<<<NB, 256, 0, stream>>>(deg, bsum, N);
  scan_block_kernel<<<1, 256, 0, stream>>>(bsum, boff, row_off, NB, N);
  scan_final_kernel<<<NB, 256, 0, stream>>>(deg, boff, row_off, cursor, inv_s, N);
  fill_csr_kernel<<<EB, 256, 0, stream>>>(srcv, dstv, cursor, col, E);

  prep_ux_kernel<<<(N * F + 255) / 256, 256, 0, stream>>>(x, inv_s, u_x, N * F);
  transpose_w_kernel<<<(F * H + 255) / 256, 256, 0, stream>>>(W0, Wt0, F, H);
  transpose_ws_kernel<<<(L * H * H + 255) / 256, 256, 0, stream>>>(Ws, WtS, H, H, L * H * H);

  dim3 AGG_GRID(8, (N + 15) / 16);
  int GEMM_GRID = (N + 63) / 64;

  // layer 0: agg(u_x) -> GEMM K=128 (no relu) -> uA = s*(h0+res)
  aggregate_kernel<128, 16><<<AGG_GRID, 256, 0, stream>>>(u_x, row_off, col, inv_s, aggA, N);
  gemm_kernel<128, false, true><<<GEMM_GRID, 256, 0, stream>>>(aggA, Wt0, b0, inv_s, batch, gh,
                                                               uA, N);
  // layers 1..2: agg(uA) -> GEMM relu -> uA
  for (int l = 0; l < 2; ++l) {
    aggregate_kernel<256, 32><<<AGG_GRID, 256, 0, stream>>>(uA, row_off, col, inv_s, aggA, N);
    gemm_kernel<256, true, true><<<GEMM_GRID, 256, 0, stream>>>(
        aggA, WtS + (size_t)l * H * H, bs + (size_t)l * H, inv_s, batch, gh, uA, N);
  }
  // layer 3: agg(uA) -> GEMM relu -> h (bf16)
  aggregate_kernel<256, 32><<<AGG_GRID, 256, 0, stream>>>(uA, row_off, col, inv_s, aggA, N);
  gemm_kernel<256, true, false><<<GEMM_GRID, 256, 0, stream>>>(
      aggA, WtS + (size_t)2 * H * H, bs + (size_t)2 * H, inv_s, batch, gh, hfin, N);

  int POOL_BLOCKS = 1024;
  int chunk = (N + POOL_BLOCKS - 1) / POOL_BLOCKS;
  pool_kernel<<<POOL_BLOCKS, 256, 0, stream>>>(hfin, batch, gmsum, cnt, N, chunk);
  final_kernel<<<G, 256, 0, stream>>>(gmsum, cnt, gh, Wlin, blin, out, out + (size_t)G * C, G);
}

// Round 5
// 641.817 us; speedup vs baseline: 1.2291x; 1.2291x over previous
//
#include <hip/hip_runtime.h>

// ---------------------------------------------------------------------------
// BlockGNN on MI355X, round 5: group-major (blocked-slab) XCD-sharded gather.
//   - u stored as [NG][N][CHG] (group-major): group g's slab is contiguous
//     3.2 MB -> fits one XCD's 4 MiB L2 at full 128B-line utilization.
//   - aggregate: grid.x = 8 channel groups (round-robin XCD), unroll-2 edge
//     loop (2 loads in flight per lane), col/out nontemporal.
//   - GEMM A-stage reads blocked layout directly (k-block == slab).
// ---------------------------------------------------------------------------

typedef __bf16 bf16x8 __attribute__((ext_vector_type(8)));
typedef float f32x4 __attribute__((ext_vector_type(4)));
typedef unsigned int u32x4 __attribute__((ext_vector_type(4)));

__device__ inline float bf2f(unsigned short u) {
  union { unsigned int i; float f; } v;
  v.i = (unsigned int)u << 16;
  return v.f;
}
__device__ inline unsigned short f2bf(float f) {
  union { unsigned int i; float f; } v;
  v.f = f;
  unsigned int i = v.i;
  return (unsigned short)((i + 0x7fffu + ((i >> 16) & 1u)) >> 16);  // RNE
}
__device__ inline unsigned int pack2(float a, float b) {
  return (unsigned int)f2bf(a) | ((unsigned int)f2bf(b) << 16);
}
__device__ inline void acc8(float* acc, u32x4 r) {
#pragma unroll
  for (int q = 0; q < 4; ++q) {
    acc[2 * q] += bf2f((unsigned short)(r[q] & 0xffffu));
    acc[2 * q + 1] += bf2f((unsigned short)(r[q] >> 16));
  }
}

// ----------------------------- CSR build -----------------------------------

__global__ void count_deg_kernel(const int* __restrict__ dst, int* __restrict__ deg, int E) {
  int e = blockIdx.x * blockDim.x + threadIdx.x;
  if (e < E) atomicAdd(&deg[dst[e]], 1);
}

__global__ void scan_partial_kernel(const int* __restrict__ deg, int* __restrict__ bsum, int N) {
  __shared__ int s[256];
  int i = blockIdx.x * 256 + threadIdx.x;
  s[threadIdx.x] = (i < N) ? deg[i] : 0;
  __syncthreads();
  for (int off = 128; off > 0; off >>= 1) {
    if (threadIdx.x < off) s[threadIdx.x] += s[threadIdx.x + off];
    __syncthreads();
  }
  if (threadIdx.x == 0) bsum[blockIdx.x] = s[0];
}

__global__ void scan_block_kernel(const int* __restrict__ bsum, int* __restrict__ boff,
                                  int* __restrict__ row_off, int NB, int N) {
  __shared__ int s[256];
  int v = (threadIdx.x < NB) ? bsum[threadIdx.x] : 0;
  s[threadIdx.x] = v;
  __syncthreads();
  for (int off = 1; off < 256; off <<= 1) {
    int t = (threadIdx.x >= off) ? s[threadIdx.x - off] : 0;
    __syncthreads();
    s[threadIdx.x] += t;
    __syncthreads();
  }
  boff[threadIdx.x] = s[threadIdx.x] - v;
  if (threadIdx.x == 255) row_off[N] = s[255];
}

// also computes inv_s and initializes cursor = row_off
__global__ void scan_final_kernel(const int* __restrict__ deg, const int* __restrict__ boff,
                                  int* __restrict__ row_off, int* __restrict__ cursor,
                                  float* __restrict__ inv_s, int N) {
  __shared__ int s[256];
  int i = blockIdx.x * 256 + threadIdx.x;
  int v = (i < N) ? deg[i] : 0;
  s[threadIdx.x] = v;
  __syncthreads();
  for (int off = 1; off < 256; off <<= 1) {
    int t = (threadIdx.x >= off) ? s[threadIdx.x - off] : 0;
    __syncthreads();
    s[threadIdx.x] += t;
    __syncthreads();
  }
  if (i < N) {
    int ro = boff[blockIdx.x] + s[threadIdx.x] - v;
    row_off[i] = ro;
    cursor[i] = ro;
    inv_s[i] = rsqrtf((float)(v + 1));  // +1 self loop
  }
}

__global__ void fill_csr_kernel(const int* __restrict__ src, const int* __restrict__ dst,
                                int* __restrict__ cursor, int* __restrict__ col, int E) {
  int e = blockIdx.x * blockDim.x + threadIdx.x;
  if (e < E) {
    int pos = atomicAdd(&cursor[dst[e]], 1);
    col[pos] = src[e];
  }
}

// ----------------------------- prep ----------------------------------------

// u_x blocked: u[g][i][16],  g = c>>4, c = channel in [0,128)
__global__ void prep_ux_kernel(const float* __restrict__ x, const float* __restrict__ inv_s,
                               unsigned short* __restrict__ u, int N, int total) {
  int idx = blockIdx.x * 256 + threadIdx.x;
  if (idx < total) {
    int i = idx >> 7;
    int c = idx & 127;
    int g = c >> 4;
    u[(size_t)g * N * 16 + (size_t)i * 16 + (c & 15)] = f2bf(inv_s[i] * x[idx]);
  }
}

// Wt[n][k] = bf16( W[k][n] );  W is [K][Ncol] row-major
__global__ void transpose_w_kernel(const float* __restrict__ W, unsigned short* __restrict__ Wt,
                                   int K, int Ncol) {
  int idx = blockIdx.x * 256 + threadIdx.x;
  if (idx < K * Ncol) {
    int k = idx / Ncol, n = idx - k * Ncol;
    Wt[n * K + k] = f2bf(W[idx]);
  }
}

// all L layers of Ws at once: W [L][K][Ncol] -> Wt [L][Ncol][K]
__global__ void transpose_ws_kernel(const float* __restrict__ W, unsigned short* __restrict__ Wt,
                                    int K, int Ncol, int total) {
  int idx = blockIdx.x * 256 + threadIdx.x;
  if (idx < total) {
    int l = idx / (K * Ncol);
    int rem = idx - l * K * Ncol;
    int k = rem / Ncol, n = rem - k * Ncol;
    Wt[l * K * Ncol + n * K + k] = f2bf(W[idx]);
  }
}

// ----------------------------- aggregate ------------------------------------
// Blocked u: [8][N][CHG]. Group g = blockIdx.x (round-robin XCD).
// Wave = 4 nodes x 16 lanes; per node SLOTS edge slots x LPR 16B-lanes.
// out_i = bf16( s_i * ( u_i + sum_j u_j ) ), written blocked, nontemporal.
template <int CHG>
__global__ __launch_bounds__(256) void aggregate_kernel(
    const unsigned short* __restrict__ u, const int* __restrict__ row_off,
    const int* __restrict__ col, const float* __restrict__ inv_s,
    unsigned short* __restrict__ out, int N) {
  constexpr int LPR = CHG / 8;     // lanes per slice (16B each): 4 or 2
  constexpr int SLOTS = 16 / LPR;  // edge slots per node: 4 or 8
  int g = blockIdx.x;
  int lane = threadIdx.x & 63;
  int wave = threadIdx.x >> 6;
  int i = blockIdx.y * 16 + wave * 4 + (lane >> 4);
  if (i >= N) return;
  int l16 = lane & 15;
  int sub = l16 / LPR;
  int c = l16 % LPR;
  const unsigned short* ug = u + (size_t)g * N * CHG + c * 8;  // slab base + lane offset
  int e0 = row_off[i], e1 = row_off[i + 1];
  float acc[8] = {};
  int e = e0 + sub;
  for (; e + SLOTS < e1; e += 2 * SLOTS) {
    int j0 = __builtin_nontemporal_load(&col[e]);
    int j1 = __builtin_nontemporal_load(&col[e + SLOTS]);
    u32x4 r0 = *(const u32x4*)&ug[(size_t)j0 * CHG];
    u32x4 r1 = *(const u32x4*)&ug[(size_t)j1 * CHG];
    acc8(acc, r0);
    acc8(acc, r1);
  }
  if (e < e1) {
    int j = __builtin_nontemporal_load(&col[e]);
    u32x4 r = *(const u32x4*)&ug[(size_t)j * CHG];
    acc8(acc, r);
  }
#pragma unroll
  for (int k = 0; k < 8; ++k) {
#pragma unroll
    for (int off = 8; off >= LPR; off >>= 1) acc[k] += __shfl_down(acc[k], off);
  }
  if (l16 < LPR) {
    u32x4 self = *(const u32x4*)&ug[(size_t)i * CHG];
    acc8(acc, self);
    float s = inv_s[i];
    u32x4 o;
    o[0] = pack2(s * acc[0], s * acc[1]);
    o[1] = pack2(s * acc[2], s * acc[3]);
    o[2] = pack2(s * acc[4], s * acc[5]);
    o[3] = pack2(s * acc[6], s * acc[7]);
    __builtin_nontemporal_store(o, (u32x4*)&out[(size_t)g * N * CHG + (size_t)i * CHG + c * 8]);
  }
}

// ----------------------------- MFMA GEMM ------------------------------------
// A is blocked [K/CHG][M][CHG] bf16. C[M,256] = A @ W (+bias, opt relu).
// WRITE_U: out = blocked [8][M][32] bf16 of inv_s[r]*(C+gh[batch[r]])
// else:    out = row-major [M][256] bf16 of C
template <int K, int CHG, bool RELU, bool WRITE_U>
__global__ __launch_bounds__(256) void gemm_kernel(
    const unsigned short* __restrict__ A,   // blocked
    const unsigned short* __restrict__ Bt,  // [256][K] bf16 (W transposed)
    const float* __restrict__ bias,         // [256]
    const float* __restrict__ inv_s, const int* __restrict__ batch,
    const float* __restrict__ gh,           // [G][256]
    unsigned short* __restrict__ out, int M) {
  constexpr int BK = 32;
  constexpr int LDT = 40;  // padded stride in ushorts (80B, 16B-aligned)
  __shared__ unsigned short As[64 * LDT];
  __shared__ unsigned short Bs[256 * LDT];
  int tid = threadIdx.x;
  int wave = tid >> 6, lane = tid & 63;
  int quad = lane >> 4, l15 = lane & 15;
  int row0 = blockIdx.x * 64;
  f32x4 acc[4][4];
#pragma unroll
  for (int m = 0; m < 4; ++m)
#pragma unroll
    for (int n = 0; n < 4; ++n) acc[m][n] = (f32x4){0.f, 0.f, 0.f, 0.f};

  for (int k0 = 0; k0 < K; k0 += BK) {
    {  // stage A: 64 rows x 32 k, from blocked layout
      int r = tid >> 2, kq = tid & 3;
      int gr = row0 + r;
      int kk = k0 + kq * 8;
      int g = kk / CHG, ko = kk % CHG;
      u32x4 v = (u32x4){0u, 0u, 0u, 0u};
      if (gr < M) v = *(const u32x4*)&A[(size_t)g * M * CHG + (size_t)gr * CHG + ko];
      *(u32x4*)&As[r * LDT + kq * 8] = v;
    }
#pragma unroll
    for (int p = 0; p < 4; ++p) {  // stage B: 256 rows x 32 k
      int n = (tid >> 2) + p * 64, kq = tid & 3;
      *(u32x4*)&Bs[n * LDT + kq * 8] = *(const u32x4*)&Bt[(size_t)n * K + k0 + kq * 8];
    }
    __syncthreads();
    bf16x8 af[4], bfr[4];
#pragma unroll
    for (int m = 0; m < 4; ++m)
      af[m] = __builtin_bit_cast(bf16x8, *(const u32x4*)&As[(m * 16 + l15) * LDT + quad * 8]);
#pragma unroll
    for (int n = 0; n < 4; ++n)
      bfr[n] = __builtin_bit_cast(bf16x8,
                                  *(const u32x4*)&Bs[(wave * 64 + n * 16 + l15) * LDT + quad * 8]);
#pragma unroll
    for (int m = 0; m < 4; ++m)
#pragma unroll
      for (int n = 0; n < 4; ++n)
        acc[m][n] = __builtin_amdgcn_mfma_f32_16x16x32_bf16(af[m], bfr[n], acc[m][n], 0, 0, 0);
    __syncthreads();
  }
  // epilogue: C/D map col=lane&15, row=(lane>>4)*4+reg
#pragma unroll
  for (int m = 0; m < 4; ++m) {
#pragma unroll
    for (int r = 0; r < 4; ++r) {
      int gr = row0 + m * 16 + quad * 4 + r;
      if (gr >= M) continue;
      float sv = 1.0f;
      int bofs = 0;
      if (WRITE_U) {
        sv = inv_s[gr];
        bofs = batch[gr] * 256;
      }
#pragma unroll
      for (int n = 0; n < 4; ++n) {
        int cc = wave * 64 + n * 16 + l15;
        float v = acc[m][n][r] + bias[cc];
        if (RELU) v = fmaxf(v, 0.f);
        if (WRITE_U) {
          v = sv * (v + gh[bofs + cc]);
          out[(size_t)(cc >> 5) * M * 32 + (size_t)gr * 32 + (cc & 31)] = f2bf(v);
        } else {
          out[(size_t)gr * 256 + cc] = f2bf(v);
        }
      }
    }
  }
}

// ----------------------------- pool + final ---------------------------------

__global__ void pool_kernel(const unsigned short* __restrict__ h, const int* __restrict__ batch,
                            float* __restrict__ gmsum, float* __restrict__ cnt, int N, int chunk) {
  int start = blockIdx.x * chunk;
  int end = min(start + chunk, N);
  if (start >= end) return;
  int c = threadIdx.x;
  int g = batch[start];
  float acc = 0.0f;
  int run = 0;
  for (int n = start; n < end; ++n) {
    int bg = batch[n];
    if (bg != g) {
      atomicAdd(&gmsum[g * 256 + c], acc);
      if (c == 0) atomicAdd(&cnt[g], (float)run);
      acc = 0.0f;
      run = 0;
      g = bg;
    }
    acc += bf2f(h[(size_t)n * 256 + c]);
    run++;
  }
  atomicAdd(&gmsum[g * 256 + c], acc);
  if (c == 0) atomicAdd(&cnt[g], (float)run);
}

__global__ void final_kernel(const float* __restrict__ gmsum, const float* __restrict__ cnt,
                             const float* __restrict__ gh, const float* __restrict__ Wlin,
                             const float* __restrict__ blin, float* __restrict__ y,
                             float* __restrict__ gm_out, int G) {
  int g = blockIdx.x;
  int c = threadIdx.x;
  __shared__ float row[256];
  float v = gmsum[g * 256 + c] / fmaxf(cnt[g], 1.0f) + gh[g * 256 + c];
  gm_out[g * 256 + c] = v;
  row[c] = v;
  __syncthreads();
  if (c < 10) {
    float acc = blin[c];
    for (int k = 0; k < 256; ++k) acc += row[k] * Wlin[k * 10 + c];
    y[g * 10 + c] = acc;
  }
}

// ----------------------------- launch ----------------------------------------

extern "C" void kernel_launch(void* const* d_in, const int* in_sizes, int n_in,
                              void* d_out, int out_size, void* d_ws, size_t ws_size,
                              hipStream_t stream) {
  const float* x = (const float*)d_in[0];
  const int* ei = (const int*)d_in[1];
  const int* batch = (const int*)d_in[2];
  const float* gh = (const float*)d_in[3];
  const float* W0 = (const float*)d_in[4];
  const float* b0 = (const float*)d_in[5];
  const float* Ws = (const float*)d_in[6];
  const float* bs = (const float*)d_in[7];
  const float* Wlin = (const float*)d_in[8];
  const float* blin = (const float*)d_in[9];
  float* out = (float*)d_out;

  const int N = in_sizes[2];
  const int E = in_sizes[1] / 2;
  const int G = in_sizes[3] / 256;
  const int H = 256, L = 3, C = 10, F = 128;

  char* ws = (char*)d_ws;
  size_t off = 0;
  auto alloc = [&](size_t bytes) {
    void* p = ws + off;
    off += (bytes + 255) & ~(size_t)255;
    return p;
  };
  int* deg = (int*)alloc((size_t)N * 4);
  int* cursor = (int*)alloc((size_t)N * 4);
  int* row_off = (int*)alloc((size_t)(N + 1) * 4);
  int* bsum = (int*)alloc(256 * 4);
  int* boff = (int*)alloc(256 * 4);
  int* col = (int*)alloc((size_t)E * 4);
  float* inv_s = (float*)alloc((size_t)N * 4);
  float* cnt = (float*)alloc((size_t)G * 4);
  float* gmsum = (float*)alloc((size_t)G * H * 4);
  unsigned short* u_x = (unsigned short*)alloc((size_t)N * F * 2);   // blocked [8][N][16]
  unsigned short* uA = (unsigned short*)alloc((size_t)N * H * 2);    // blocked [8][N][32]
  unsigned short* aggA = (unsigned short*)alloc((size_t)N * H * 2);  // blocked agg out
  unsigned short* hfin = (unsigned short*)alloc((size_t)N * H * 2);  // row-major final h
  unsigned short* Wt0 = (unsigned short*)alloc((size_t)F * H * 2);   // [256][128]
  unsigned short* WtS = (unsigned short*)alloc((size_t)L * H * H * 2);

  const int* srcv = ei;
  const int* dstv = ei + E;

  (void)hipMemsetAsync(deg, 0, (size_t)N * 4, stream);
  (void)hipMemsetAsync(cnt, 0, (size_t)(((char*)gmsum - (char*)cnt)) + (size_t)G * H * 4, stream);

  int EB = (E + 255) / 256;
  int NB = (N + 255) / 256;
  count_deg_kernel<<<EB, 256, 0, stream>>>(dstv, deg, E);
  scan_partial_kernel<<<NB, 256, 0, stream>>>(deg, bsum, N);
  scan_block_kernel<<<1, 256, 0, stream>>>(bsum, boff, row_off, NB, N);
  scan_final_kernel<<<NB, 256, 0, stream>>>(deg, boff, row_off, cursor, inv_s, N);
  fill_csr_kernel<<<EB, 256, 0, stream>>>(srcv, dstv, cursor, col, E);

  prep_ux_kernel<<<(N * F + 255) / 256, 256, 0, stream>>>(x, inv_s, u_x, N, N * F);
  transpose_w_kernel<<<(F * H + 255) / 256, 256, 0, stream>>>(W0, Wt0, F, H);
  transpose_ws_kernel<<<(L * H * H + 255) / 256, 256, 0, stream>>>(Ws, WtS, H, H, L * H * H);

  dim3 AGG_GRID(8, (N + 15) / 16);
  int GEMM_GRID = (N + 63) / 64;

  // layer 0: agg(u_x) -> GEMM K=128 (no relu) -> uA = blocked s*(h0+res)
  aggregate_kernel<16><<<AGG_GRID, 256, 0, stream>>>(u_x, row_off, col, inv_s, aggA, N);
  gemm_kernel<128, 16, false, true><<<GEMM_GRID, 256, 0, stream>>>(aggA, Wt0, b0, inv_s, batch,
                                                                   gh, uA, N);
  // layers 1..2: agg(uA) -> GEMM relu -> uA
  for (int l = 0; l < 2; ++l) {
    aggregate_kernel<32><<<AGG_GRID, 256, 0, stream>>>(uA, row_off, col, inv_s, aggA, N);
    gemm_kernel<256, 32, true, true><<<GEMM_GRID, 256, 0, stream>>>(
        aggA, WtS + (size_t)l * H * H, bs + (size_t)l * H, inv_s, batch, gh, uA, N);
  }
  // layer 3: agg(uA) -> GEMM relu -> h (row-major bf16)
  aggregate_kernel<32><<<AGG_GRID, 256, 0, stream>>>(uA, row_off, col, inv_s, aggA, N);
  gemm_kernel<256, 32, true, false><<<GEMM_GRID, 256, 0, stream>>>(
      aggA, WtS + (size_t)2 * H * H, bs + (size_t)2 * H, inv_s, batch, gh, hfin, N);

  int POOL_BLOCKS = 1024;
  int chunk = (N + POOL_BLOCKS - 1) / POOL_BLOCKS;
  pool_kernel<<<POOL_BLOCKS, 256, 0, stream>>>(hfin, batch, gmsum, cnt, N, chunk);
  final_kernel<<<G, 256, 0, stream>>>(gmsum, cnt, gh, Wlin, blin, out, out + (size_t)G * C, G);
}

// Round 6
// 639.510 us; speedup vs baseline: 1.2335x; 1.0036x over previous
//
#include <hip/hip_runtime.h>

// ---------------------------------------------------------------------------
// BlockGNN on MI355X, round 6.
//   - blocked u slabs [8][N][CHG] (L2-resident per XCD), as in R5
//   - aggregate: unroll-4 (4 gathers in flight/lane), packed float2 accum
//   - GEMM: 128x256 tile (halved B-staging per output), launch_bounds(256,2)
// ---------------------------------------------------------------------------

typedef __bf16 bf16x8 __attribute__((ext_vector_type(8)));
typedef float f32x4 __attribute__((ext_vector_type(4)));
typedef float f32x2 __attribute__((ext_vector_type(2)));
typedef unsigned int u32x4 __attribute__((ext_vector_type(4)));

__device__ inline unsigned short f2bf(float f) {
  union { unsigned int i; float f; } v;
  v.f = f;
  unsigned int i = v.i;
  return (unsigned short)((i + 0x7fffu + ((i >> 16) & 1u)) >> 16);  // RNE
}
__device__ inline float bf2f(unsigned short u) {
  union { unsigned int i; float f; } v;
  v.i = (unsigned int)u << 16;
  return v.f;
}
__device__ inline unsigned int pack2(float a, float b) {
  return (unsigned int)f2bf(a) | ((unsigned int)f2bf(b) << 16);
}
// packed accumulate: a[q] += {fp32(lo bf16), fp32(hi bf16)} of r[q]
__device__ inline void accp(f32x2* a, u32x4 r) {
#pragma unroll
  for (int q = 0; q < 4; ++q) {
    union { unsigned int i; float f; } lo, hi;
    lo.i = r[q] << 16;
    hi.i = r[q] & 0xffff0000u;
    f32x2 t = {lo.f, hi.f};
    a[q] += t;
  }
}

// ----------------------------- CSR build -----------------------------------

__global__ void count_deg_kernel(const int* __restrict__ dst, int* __restrict__ deg, int E) {
  int e = blockIdx.x * blockDim.x + threadIdx.x;
  if (e < E) atomicAdd(&deg[dst[e]], 1);
}

__global__ void scan_partial_kernel(const int* __restrict__ deg, int* __restrict__ bsum, int N) {
  __shared__ int s[256];
  int i = blockIdx.x * 256 + threadIdx.x;
  s[threadIdx.x] = (i < N) ? deg[i] : 0;
  __syncthreads();
  for (int off = 128; off > 0; off >>= 1) {
    if (threadIdx.x < off) s[threadIdx.x] += s[threadIdx.x + off];
    __syncthreads();
  }
  if (threadIdx.x == 0) bsum[blockIdx.x] = s[0];
}

__global__ void scan_block_kernel(const int* __restrict__ bsum, int* __restrict__ boff,
                                  int* __restrict__ row_off, int NB, int N) {
  __shared__ int s[256];
  int v = (threadIdx.x < NB) ? bsum[threadIdx.x] : 0;
  s[threadIdx.x] = v;
  __syncthreads();
  for (int off = 1; off < 256; off <<= 1) {
    int t = (threadIdx.x >= off) ? s[threadIdx.x - off] : 0;
    __syncthreads();
    s[threadIdx.x] += t;
    __syncthreads();
  }
  boff[threadIdx.x] = s[threadIdx.x] - v;
  if (threadIdx.x == 255) row_off[N] = s[255];
}

// also computes inv_s and initializes cursor = row_off
__global__ void scan_final_kernel(const int* __restrict__ deg, const int* __restrict__ boff,
                                  int* __restrict__ row_off, int* __restrict__ cursor,
                                  float* __restrict__ inv_s, int N) {
  __shared__ int s[256];
  int i = blockIdx.x * 256 + threadIdx.x;
  int v = (i < N) ? deg[i] : 0;
  s[threadIdx.x] = v;
  __syncthreads();
  for (int off = 1; off < 256; off <<= 1) {
    int t = (threadIdx.x >= off) ? s[threadIdx.x - off] : 0;
    __syncthreads();
    s[threadIdx.x] += t;
    __syncthreads();
  }
  if (i < N) {
    int ro = boff[blockIdx.x] + s[threadIdx.x] - v;
    row_off[i] = ro;
    cursor[i] = ro;
    inv_s[i] = rsqrtf((float)(v + 1));  // +1 self loop
  }
}

__global__ void fill_csr_kernel(const int* __restrict__ src, const int* __restrict__ dst,
                                int* __restrict__ cursor, int* __restrict__ col, int E) {
  int e = blockIdx.x * blockDim.x + threadIdx.x;
  if (e < E) {
    int pos = atomicAdd(&cursor[dst[e]], 1);
    col[pos] = src[e];
  }
}

// ----------------------------- prep ----------------------------------------

// u_x blocked: u[g][i][16],  g = c>>4
__global__ void prep_ux_kernel(const float* __restrict__ x, const float* __restrict__ inv_s,
                               unsigned short* __restrict__ u, int N, int total) {
  int idx = blockIdx.x * 256 + threadIdx.x;
  if (idx < total) {
    int i = idx >> 7;
    int c = idx & 127;
    int g = c >> 4;
    u[(size_t)g * N * 16 + (size_t)i * 16 + (c & 15)] = f2bf(inv_s[i] * x[idx]);
  }
}

__global__ void transpose_w_kernel(const float* __restrict__ W, unsigned short* __restrict__ Wt,
                                   int K, int Ncol) {
  int idx = blockIdx.x * 256 + threadIdx.x;
  if (idx < K * Ncol) {
    int k = idx / Ncol, n = idx - k * Ncol;
    Wt[n * K + k] = f2bf(W[idx]);
  }
}

__global__ void transpose_ws_kernel(const float* __restrict__ W, unsigned short* __restrict__ Wt,
                                    int K, int Ncol, int total) {
  int idx = blockIdx.x * 256 + threadIdx.x;
  if (idx < total) {
    int l = idx / (K * Ncol);
    int rem = idx - l * K * Ncol;
    int k = rem / Ncol, n = rem - k * Ncol;
    Wt[l * K * Ncol + n * K + k] = f2bf(W[idx]);
  }
}

// ----------------------------- aggregate ------------------------------------
// Blocked u: [8][N][CHG]. Group g = blockIdx.x (round-robin XCD).
// Wave = 4 nodes x 16 lanes; per node SLOTS edge slots x LPR 16B-lanes.
// Unroll-4: 4 independent gathers in flight per lane.
template <int CHG>
__global__ __launch_bounds__(256) void aggregate_kernel(
    const unsigned short* __restrict__ u, const int* __restrict__ row_off,
    const int* __restrict__ col, const float* __restrict__ inv_s,
    unsigned short* __restrict__ out, int N) {
  constexpr int LPR = CHG / 8;     // lanes per slice (16B each): 4 or 2
  constexpr int SLOTS = 16 / LPR;  // edge slots per node: 4 or 8
  int g = blockIdx.x;
  int lane = threadIdx.x & 63;
  int wave = threadIdx.x >> 6;
  int i = blockIdx.y * 16 + wave * 4 + (lane >> 4);
  if (i >= N) return;
  int l16 = lane & 15;
  int sub = l16 / LPR;
  int c = l16 % LPR;
  const unsigned short* ug = u + (size_t)g * N * CHG + c * 8;
  int e0 = row_off[i], e1 = row_off[i + 1];
  f32x2 a[4] = {};
  int e = e0 + sub;
  for (; e + 3 * SLOTS < e1; e += 4 * SLOTS) {
    int j0 = __builtin_nontemporal_load(&col[e]);
    int j1 = __builtin_nontemporal_load(&col[e + SLOTS]);
    int j2 = __builtin_nontemporal_load(&col[e + 2 * SLOTS]);
    int j3 = __builtin_nontemporal_load(&col[e + 3 * SLOTS]);
    u32x4 r0 = *(const u32x4*)&ug[(size_t)j0 * CHG];
    u32x4 r1 = *(const u32x4*)&ug[(size_t)j1 * CHG];
    u32x4 r2 = *(const u32x4*)&ug[(size_t)j2 * CHG];
    u32x4 r3 = *(const u32x4*)&ug[(size_t)j3 * CHG];
    accp(a, r0);
    accp(a, r1);
    accp(a, r2);
    accp(a, r3);
  }
  for (; e < e1; e += SLOTS) {
    int j = __builtin_nontemporal_load(&col[e]);
    u32x4 r = *(const u32x4*)&ug[(size_t)j * CHG];
    accp(a, r);
  }
#pragma unroll
  for (int q = 0; q < 4; ++q) {
#pragma unroll
    for (int off = 8; off >= LPR; off >>= 1) {
      a[q][0] += __shfl_down(a[q][0], off);
      a[q][1] += __shfl_down(a[q][1], off);
    }
  }
  if (l16 < LPR) {
    u32x4 self = *(const u32x4*)&ug[(size_t)i * CHG];
    accp(a, self);
    float s = inv_s[i];
    u32x4 o;
    o[0] = pack2(s * a[0][0], s * a[0][1]);
    o[1] = pack2(s * a[1][0], s * a[1][1]);
    o[2] = pack2(s * a[2][0], s * a[2][1]);
    o[3] = pack2(s * a[3][0], s * a[3][1]);
    __builtin_nontemporal_store(o, (u32x4*)&out[(size_t)g * N * CHG + (size_t)i * CHG + c * 8]);
  }
}

// ----------------------------- MFMA GEMM ------------------------------------
// A blocked [K/CHG][M][CHG] bf16. C[M,256] = A @ W (+bias, opt relu).
// 128x256 tile per block, 4 waves (each: 128 rows x 64 cols).
// WRITE_U: out = blocked [8][M][32] bf16 of inv_s[r]*(C+gh[batch[r]])
// else:    out = row-major [M][256] bf16 of C
template <int K, int CHG, bool RELU, bool WRITE_U>
__global__ __launch_bounds__(256, 2) void gemm_kernel(
    const unsigned short* __restrict__ A,   // blocked
    const unsigned short* __restrict__ Bt,  // [256][K] bf16 (W transposed)
    const float* __restrict__ bias,         // [256]
    const float* __restrict__ inv_s, const int* __restrict__ batch,
    const float* __restrict__ gh,           // [G][256]
    unsigned short* __restrict__ out, int M) {
  constexpr int BK = 32;
  constexpr int LDT = 40;  // padded stride in ushorts (80B, 16B-aligned)
  __shared__ unsigned short As[128 * LDT];
  __shared__ unsigned short Bs[256 * LDT];
  int tid = threadIdx.x;
  int wave = tid >> 6, lane = tid & 63;
  int quad = lane >> 4, l15 = lane & 15;
  int row0 = blockIdx.x * 128;
  f32x4 acc[8][4];
#pragma unroll
  for (int m = 0; m < 8; ++m)
#pragma unroll
    for (int n = 0; n < 4; ++n) acc[m][n] = (f32x4){0.f, 0.f, 0.f, 0.f};

  for (int k0 = 0; k0 < K; k0 += BK) {
#pragma unroll
    for (int p = 0; p < 2; ++p) {  // stage A: 128 rows x 32 k
      int r = (tid >> 2) + p * 64, kq = tid & 3;
      int gr = row0 + r;
      int kk = k0 + kq * 8;
      int g = kk / CHG, ko = kk % CHG;
      u32x4 v = (u32x4){0u, 0u, 0u, 0u};
      if (gr < M) v = *(const u32x4*)&A[(size_t)g * M * CHG + (size_t)gr * CHG + ko];
      *(u32x4*)&As[r * LDT + kq * 8] = v;
    }
#pragma unroll
    for (int p = 0; p < 4; ++p) {  // stage B: 256 rows x 32 k
      int n = (tid >> 2) + p * 64, kq = tid & 3;
      *(u32x4*)&Bs[n * LDT + kq * 8] = *(const u32x4*)&Bt[(size_t)n * K + k0 + kq * 8];
    }
    __syncthreads();
    bf16x8 af[8], bfr[4];
#pragma unroll
    for (int m = 0; m < 8; ++m)
      af[m] = __builtin_bit_cast(bf16x8, *(const u32x4*)&As[(m * 16 + l15) * LDT + quad * 8]);
#pragma unroll
    for (int n = 0; n < 4; ++n)
      bfr[n] = __builtin_bit_cast(bf16x8,
                                  *(const u32x4*)&Bs[(wave * 64 + n * 16 + l15) * LDT + quad * 8]);
#pragma unroll
    for (int m = 0; m < 8; ++m)
#pragma unroll
      for (int n = 0; n < 4; ++n)
        acc[m][n] = __builtin_amdgcn_mfma_f32_16x16x32_bf16(af[m], bfr[n], acc[m][n], 0, 0, 0);
    __syncthreads();
  }
  // epilogue: C/D map col=lane&15, row=(lane>>4)*4+reg
#pragma unroll
  for (int m = 0; m < 8; ++m) {
#pragma unroll
    for (int r = 0; r < 4; ++r) {
      int gr = row0 + m * 16 + quad * 4 + r;
      if (gr >= M) continue;
      float sv = 1.0f;
      int bofs = 0;
      if (WRITE_U) {
        sv = inv_s[gr];
        bofs = batch[gr] * 256;
      }
#pragma unroll
      for (int n = 0; n < 4; ++n) {
        int cc = wave * 64 + n * 16 + l15;
        float v = acc[m][n][r] + bias[cc];
        if (RELU) v = fmaxf(v, 0.f);
        if (WRITE_U) {
          v = sv * (v + gh[bofs + cc]);
          out[(size_t)(cc >> 5) * M * 32 + (size_t)gr * 32 + (cc & 31)] = f2bf(v);
        } else {
          out[(size_t)gr * 256 + cc] = f2bf(v);
        }
      }
    }
  }
}

// ----------------------------- pool + final ---------------------------------

__global__ void pool_kernel(const unsigned short* __restrict__ h, const int* __restrict__ batch,
                            float* __restrict__ gmsum, float* __restrict__ cnt, int N, int chunk) {
  int start = blockIdx.x * chunk;
  int end = min(start + chunk, N);
  if (start >= end) return;
  int c = threadIdx.x;
  int g = batch[start];
  float acc = 0.0f;
  int run = 0;
  for (int n = start; n < end; ++n) {
    int bg = batch[n];
    if (bg != g) {
      atomicAdd(&gmsum[g * 256 + c], acc);
      if (c == 0) atomicAdd(&cnt[g], (float)run);
      acc = 0.0f;
      run = 0;
      g = bg;
    }
    acc += bf2f(h[(size_t)n * 256 + c]);
    run++;
  }
  atomicAdd(&gmsum[g * 256 + c], acc);
  if (c == 0) atomicAdd(&cnt[g], (float)run);
}

__global__ void final_kernel(const float* __restrict__ gmsum, const float* __restrict__ cnt,
                             const float* __restrict__ gh, const float* __restrict__ Wlin,
                             const float* __restrict__ blin, float* __restrict__ y,
                             float* __restrict__ gm_out, int G) {
  int g = blockIdx.x;
  int c = threadIdx.x;
  __shared__ float row[256];
  float v = gmsum[g * 256 + c] / fmaxf(cnt[g], 1.0f) + gh[g * 256 + c];
  gm_out[g * 256 + c] = v;
  row[c] = v;
  __syncthreads();
  if (c < 10) {
    float acc = blin[c];
    for (int k = 0; k < 256; ++k) acc += row[k] * Wlin[k * 10 + c];
    y[g * 10 + c] = acc;
  }
}

// ----------------------------- launch ----------------------------------------

extern "C" void kernel_launch(void* const* d_in, const int* in_sizes, int n_in,
                              void* d_out, int out_size, void* d_ws, size_t ws_size,
                              hipStream_t stream) {
  const float* x = (const float*)d_in[0];
  const int* ei = (const int*)d_in[1];
  const int* batch = (const int*)d_in[2];
  const float* gh = (const float*)d_in[3];
  const float* W0 = (const float*)d_in[4];
  const float* b0 = (const float*)d_in[5];
  const float* Ws = (const float*)d_in[6];
  const float* bs = (const float*)d_in[7];
  const float* Wlin = (const float*)d_in[8];
  const float* blin = (const float*)d_in[9];
  float* out = (float*)d_out;

  const int N = in_sizes[2];
  const int E = in_sizes[1] / 2;
  const int G = in_sizes[3] / 256;
  const int H = 256, L = 3, C = 10, F = 128;

  char* ws = (char*)d_ws;
  size_t off = 0;
  auto alloc = [&](size_t bytes) {
    void* p = ws + off;
    off += (bytes + 255) & ~(size_t)255;
    return p;
  };
  int* deg = (int*)alloc((size_t)N * 4);
  int* cursor = (int*)alloc((size_t)N * 4);
  int* row_off = (int*)alloc((size_t)(N + 1) * 4);
  int* bsum = (int*)alloc(256 * 4);
  int* boff = (int*)alloc(256 * 4);
  int* col = (int*)alloc((size_t)E * 4);
  float* inv_s = (float*)alloc((size_t)N * 4);
  float* cnt = (float*)alloc((size_t)G * 4);
  float* gmsum = (float*)alloc((size_t)G * H * 4);
  unsigned short* u_x = (unsigned short*)alloc((size_t)N * F * 2);   // blocked [8][N][16]
  unsigned short* uA = (unsigned short*)alloc((size_t)N * H * 2);    // blocked [8][N][32]
  unsigned short* aggA = (unsigned short*)alloc((size_t)N * H * 2);  // blocked agg out
  unsigned short* hfin = (unsigned short*)alloc((size_t)N * H * 2);  // row-major final h
  unsigned short* Wt0 = (unsigned short*)alloc((size_t)F * H * 2);   // [256][128]
  unsigned short* WtS = (unsigned short*)alloc((size_t)L * H * H * 2);

  const int* srcv = ei;
  const int* dstv = ei + E;

  (void)hipMemsetAsync(deg, 0, (size_t)N * 4, stream);
  (void)hipMemsetAsync(cnt, 0, (size_t)(((char*)gmsum - (char*)cnt)) + (size_t)G * H * 4, stream);

  int EB = (E + 255) / 256;
  int NB = (N + 255) / 256;
  count_deg_kernel<<<EB, 256, 0, stream>>>(dstv, deg, E);
  scan_partial_kernel<<<NB, 256, 0, stream>>>(deg, bsum, N);
  scan_block_kernel<<<1, 256, 0, stream>>>(bsum, boff, row_off, NB, N);
  scan_final_kernel<<<NB, 256, 0, stream>>>(deg, boff, row_off, cursor, inv_s, N);
  fill_csr_kernel<<<EB, 256, 0, stream>>>(srcv, dstv, cursor, col, E);

  prep_ux_kernel<<<(N * F + 255) / 256, 256, 0, stream>>>(x, inv_s, u_x, N, N * F);
  transpose_w_kernel<<<(F * H + 255) / 256, 256, 0, stream>>>(W0, Wt0, F, H);
  transpose_ws_kernel<<<(L * H * H + 255) / 256, 256, 0, stream>>>(Ws, WtS, H, H, L * H * H);

  dim3 AGG_GRID(8, (N + 15) / 16);
  int GEMM_GRID = (N + 127) / 128;

  // layer 0: agg(u_x) -> GEMM K=128 (no relu) -> uA = blocked s*(h0+res)
  aggregate_kernel<16><<<AGG_GRID, 256, 0, stream>>>(u_x, row_off, col, inv_s, aggA, N);
  gemm_kernel<128, 16, false, true><<<GEMM_GRID, 256, 0, stream>>>(aggA, Wt0, b0, inv_s, batch,
                                                                   gh, uA, N);
  // layers 1..2: agg(uA) -> GEMM relu -> uA
  for (int l = 0; l < 2; ++l) {
    aggregate_kernel<32><<<AGG_GRID, 256, 0, stream>>>(uA, row_off, col, inv_s, aggA, N);
    gemm_kernel<256, 32, true, true><<<GEMM_GRID, 256, 0, stream>>>(
        aggA, WtS + (size_t)l * H * H, bs + (size_t)l * H, inv_s, batch, gh, uA, N);
  }
  // layer 3: agg(uA) -> GEMM relu -> h (row-major bf16)
  aggregate_kernel<32><<<AGG_GRID, 256, 0, stream>>>(uA, row_off, col, inv_s, aggA, N);
  gemm_kernel<256, 32, true, false><<<GEMM_GRID, 256, 0, stream>>>(
      aggA, WtS + (size_t)2 * H * H, bs + (size_t)2 * H, inv_s, batch, gh, hfin, N);

  int POOL_BLOCKS = 1024;
  int chunk = (N + POOL_BLOCKS - 1) / POOL_BLOCKS;
  pool_kernel<<<POOL_BLOCKS, 256, 0, stream>>>(hfin, batch, gmsum, cnt, N, chunk);
  final_kernel<<<G, 256, 0, stream>>>(gmsum, cnt, gh, Wlin, blin, out, out + (size_t)G * C, G);
}